// Round 2
// baseline (256.070 us; speedup 1.0000x reference)
//
#include <hip/hip_runtime.h>

#define NB 8732
#define NC 21
#define BATCH 128
#define TILE 256
// LDS staging window: up to 3 (alignment shift) + 256*21 dwords, rounded up
#define CBUF 5384

__device__ inline float wred_f(float v) {
#pragma unroll
    for (int o = 32; o > 0; o >>= 1) v += __shfl_down(v, o, 64);
    return v;
}
__device__ inline int wred_i(int v) {
#pragma unroll
    for (int o = 32; o > 0; o >>= 1) v += __shfl_down(v, o, 64);
    return v;
}

// Per-box CE + smooth-L1, conf staged through LDS for coalescing.
__global__ void __launch_bounds__(256)
kA(const float* __restrict__ locp, const float* __restrict__ loct,
   const float* __restrict__ conf, const int* __restrict__ lab,
   float* __restrict__ row_ce, float* __restrict__ row_pce,
   int* __restrict__ row_np, float* __restrict__ loc_acc,
   int* __restrict__ nm_acc) {
    __shared__ float cb[CBUF];
    const int r = blockIdx.y;
    const int b0 = blockIdx.x * TILE;
    const int cnt = min(TILE, NB - b0);

    // ---- coalesced float4 staging of the conf tile ----
    const size_t o0 = ((size_t)r * NB + b0) * NC;   // dword offset of tile start
    const size_t a0 = o0 & ~(size_t)3;              // 16B-aligned window start
    const int shift = (int)(o0 - a0);
    const int ndw = shift + cnt * NC;
    const int nvec = (ndw + 3) >> 2;                // float4 count (safe: total dwords %4==0)
    const float4* src = (const float4*)(conf + a0);
    for (int v = threadIdx.x; v < nvec; v += 256) {
        float4 x = src[v];
        cb[4 * v + 0] = x.x; cb[4 * v + 1] = x.y;
        cb[4 * v + 2] = x.z; cb[4 * v + 3] = x.w;
    }
    __syncthreads();

    float ce = 0.f, pce = 0.f, ll = 0.f;
    int pc = 0;
    const int t = threadIdx.x;
    if (t < cnt) {
        const int base = shift + t * NC;            // stride 21: 2-way bank alias = free
        float c[NC];
#pragma unroll
        for (int j = 0; j < NC; j++) c[j] = cb[base + j];
        float m = c[0];
#pragma unroll
        for (int j = 1; j < NC; j++) m = fmaxf(m, c[j]);
        float s = 0.f;
#pragma unroll
        for (int j = 0; j < NC; j++) s += __expf(c[j] - m);
        const long box = (long)r * NB + b0 + t;
        const int l = lab[box];
        ce = m + __logf(s) - c[l];
        const bool pos = l > 0;

        const float4 lp = *(const float4*)(locp + box * 4);
        const float4 lt = *(const float4*)(loct + box * 4);
        float sl = 0.f, d, ad;
        d = lp.x - lt.x; ad = fabsf(d); sl += (ad < 1.f) ? 0.5f * d * d : ad - 0.5f;
        d = lp.y - lt.y; ad = fabsf(d); sl += (ad < 1.f) ? 0.5f * d * d : ad - 0.5f;
        d = lp.z - lt.z; ad = fabsf(d); sl += (ad < 1.f) ? 0.5f * d * d : ad - 0.5f;
        d = lp.w - lt.w; ad = fabsf(d); sl += (ad < 1.f) ? 0.5f * d * d : ad - 0.5f;
        if (pos) { pc = 1; pce = ce; ll = sl; }
    }

    __shared__ float sr[3][4];
    __shared__ int si[4];
    float v0 = wred_f(ce), v1 = wred_f(pce), v2 = wred_f(ll);
    int v3 = wred_i(pc);
    const int w = threadIdx.x >> 6, ln = threadIdx.x & 63;
    if (ln == 0) { sr[0][w] = v0; sr[1][w] = v1; sr[2][w] = v2; si[w] = v3; }
    __syncthreads();
    if (threadIdx.x == 0) {
        float A = 0, B = 0, C = 0; int D = 0;
#pragma unroll
        for (int k = 0; k < 4; k++) { A += sr[0][k]; B += sr[1][k]; C += sr[2][k]; D += si[k]; }
        atomicAdd(&row_ce[r], A);
        atomicAdd(&row_pce[r], B);
        atomicAdd(loc_acc, C);
        atomicAdd(&row_np[r], D);
        atomicAdd(nm_acc, D);
    }
}

__device__ inline float ce_for_box0(const float* __restrict__ cp) {
    float c[NC];
#pragma unroll
    for (int j = 0; j < NC; j++) c[j] = cp[j];
    float m = c[0];
#pragma unroll
    for (int j = 1; j < NC; j++) m = fmaxf(m, c[j]);
    float s = 0.f;
#pragma unroll
    for (int j = 0; j < NC; j++) s += __expf(c[j] - m);
    return m + __logf(s) - c[0];
}

// Per-row mining + conf accumulation; LAST block finalizes the output
// (device-scope atomics + threadfence -> no separate kC launch).
__global__ void __launch_bounds__(256)
kB(const float* __restrict__ conf, const int* __restrict__ lab,
   const float* __restrict__ row_ce, const float* __restrict__ row_pce,
   const int* __restrict__ row_np, float* __restrict__ conf_acc,
   float* __restrict__ loc_acc, int* __restrict__ nm_acc,
   int* __restrict__ done, float* __restrict__ out) {
    const int r = blockIdx.x;
    const int np = row_np[r];
    const int K = min(3 * np, NB - 1);
    const int nneg = NB - np;

    float rowval = 0.f;
    if (K >= nneg) {
        rowval = row_ce[r];                    // sel = all boxes: no sort needed
    } else if (K <= 0) {
        rowval = row_pce[r];                   // only positives selected
    } else {
        // ---- cold path: top-K among negatives via 4-round radix select ----
        __shared__ unsigned key[NB];
        __shared__ unsigned hist[256];
        __shared__ unsigned sb[2];
        for (int i = threadIdx.x; i < NB; i += 256) {
            const long box = (long)r * NB + i;
            unsigned k = 0u;
            if (lab[box] == 0) {
                float ce = ce_for_box0(conf + box * (long)NC);
                k = __float_as_uint(fmaxf(ce, 0.f));   // ce>=0: bits order-preserving
            }
            key[i] = k;
        }
        __syncthreads();
        unsigned prefix = 0;
        int Kr = K;
        for (int round = 3; round >= 0; --round) {
            const int sh = round * 8;
            const unsigned pmask = (round == 3) ? 0u : (0xFFFFFFFFu << (8 * (round + 1)));
            for (int b = threadIdx.x; b < 256; b += 256) hist[b] = 0;
            __syncthreads();
            for (int i = threadIdx.x; i < NB; i += 256) {
                const unsigned k = key[i];
                if ((k & pmask) == prefix) atomicAdd(&hist[(k >> sh) & 255u], 1u);
            }
            __syncthreads();
            if (threadIdx.x == 0) {
                unsigned cum = 0; int b = 255;
                for (; b > 0; --b) {
                    const unsigned h = hist[b];
                    if (cum + h >= (unsigned)Kr) break;
                    cum += h;
                }
                sb[0] = cum; sb[1] = (unsigned)b;
            }
            __syncthreads();
            Kr -= (int)sb[0];
            prefix |= (sb[1] << sh);
            __syncthreads();
        }
        // ties at threshold share an identical ce value -> (Kr)*val(prefix) exact
        float local = 0.f;
        for (int i = threadIdx.x; i < NB; i += 256) {
            const unsigned k = key[i];
            if (k > prefix) local += __uint_as_float(k);
        }
        __shared__ float sred[4];
        float v = wred_f(local);
        const int w = threadIdx.x >> 6, ln = threadIdx.x & 63;
        if (ln == 0) sred[w] = v;
        __syncthreads();
        rowval = row_pce[r] + sred[0] + sred[1] + sred[2] + sred[3]
               + (float)Kr * __uint_as_float(prefix);
    }

    if (threadIdx.x == 0) {
        atomicAdd(conf_acc, rowval);
        __threadfence();
        const int old = atomicAdd(done, 1);
        if (old == BATCH - 1) {                // last block finalizes
            const float cf = atomicAdd(conf_acc, 0.f);  // device-scope atomic read
            const float lc = atomicAdd(loc_acc, 0.f);
            const int nm = atomicAdd(nm_acc, 0);
            out[0] = (lc + cf) / fmaxf((float)nm, 1.f);
        }
    }
}

extern "C" void kernel_launch(void* const* d_in, const int* in_sizes, int n_in,
                              void* d_out, int out_size, void* d_ws, size_t ws_size,
                              hipStream_t stream) {
    const float* locp = (const float*)d_in[0];
    const float* loct = (const float*)d_in[1];
    const float* conf = (const float*)d_in[2];
    const int* lab = (const int*)d_in[3];
    float* out = (float*)d_out;

    // ws layout: [0]=loc_acc [1]=conf_acc [2]=nm_acc(int) [3]=done(int)
    //            [16..143]=row_ce [144..271]=row_pce [272..399]=row_np(int)
    float* loc_acc = (float*)d_ws;
    float* conf_acc = loc_acc + 1;
    int* nm_acc = (int*)d_ws + 2;
    int* done = (int*)d_ws + 3;
    float* row_ce = (float*)d_ws + 16;
    float* row_pce = row_ce + BATCH;
    int* row_np = (int*)(row_pce + BATCH);

    hipMemsetAsync(d_ws, 0, 4096, stream);

    dim3 gA((NB + TILE - 1) / TILE, BATCH);
    hipLaunchKernelGGL(kA, gA, dim3(256), 0, stream,
                       locp, loct, conf, lab, row_ce, row_pce, row_np, loc_acc, nm_acc);
    hipLaunchKernelGGL(kB, dim3(BATCH), dim3(256), 0, stream,
                       conf, lab, row_ce, row_pce, row_np, conf_acc, loc_acc, nm_acc, done, out);
}

// Round 3
// 192.888 us; speedup vs baseline: 1.3276x; 1.3276x over previous
//
#include <hip/hip_runtime.h>

#define NB 8732
#define NC 21
#define BATCH 128
#define GPT 2183   // box-groups (of 4) per row: 8732/4
#define GXB 9      // ceil(2183/256)

__device__ inline float wred_f(float v) {
#pragma unroll
    for (int o = 32; o > 0; o >>= 1) v += __shfl_down(v, o, 64);
    return v;
}
__device__ inline int wred_i(int v) {
#pragma unroll
    for (int o = 32; o > 0; o >>= 1) v += __shfl_down(v, o, 64);
    return v;
}

// compile-time component select from float4 array (folds after full unroll)
#define QV(f) (((f) & 3) == 0 ? q[(f) >> 2].x : ((f) & 3) == 1 ? q[(f) >> 2].y \
             : ((f) & 3) == 2 ? q[(f) >> 2].z : q[(f) >> 2].w)

// Thread = 4 consecutive boxes: 21 aligned dwordx4 conf loads (336 B/thread),
// 4x fewer L1 line transactions than scalar-per-class. No LDS, no barrier.
__global__ void __launch_bounds__(256)
kA(const float* __restrict__ locp, const float* __restrict__ loct,
   const float* __restrict__ conf, const int* __restrict__ lab,
   float* __restrict__ row_ce, float* __restrict__ row_pce,
   int* __restrict__ row_np, float* __restrict__ loc_acc,
   int* __restrict__ nm_acc) {
    const int r = blockIdx.y;
    const int g = blockIdx.x * 256 + threadIdx.x;   // group of 4 boxes

    float ceS = 0.f, pceS = 0.f, llS = 0.f;
    int npS = 0;

    if (g < GPT) {
        const size_t box0 = (size_t)r * NB + (size_t)g * 4;
        const float4* __restrict__ src = (const float4*)(conf + box0 * NC);
        float4 q[21];
#pragma unroll
        for (int k = 0; k < 21; k++) q[k] = src[k];

        const int4 lb4 = *(const int4*)(lab + box0);
        const int lbv[4] = {lb4.x, lb4.y, lb4.z, lb4.w};

        const float4* __restrict__ lpp = (const float4*)(locp + box0 * 4);
        const float4* __restrict__ ltp = (const float4*)(loct + box0 * 4);

#pragma unroll
        for (int b = 0; b < 4; b++) {
            const int l = lbv[b];
            float m = QV(b * 21);
#pragma unroll
            for (int j = 1; j < 21; j++) m = fmaxf(m, QV(b * 21 + j));
            float s = 0.f, gold = 0.f;
#pragma unroll
            for (int j = 0; j < 21; j++) {
                const float cv = QV(b * 21 + j);
                s += __expf(cv - m);
                gold = (j == l) ? cv : gold;
            }
            const float ce = m + __logf(s) - gold;
            ceS += ce;
            if (l > 0) {
                npS++;
                pceS += ce;
                const float4 lp = lpp[b];
                const float4 lt = ltp[b];
                float d, ad;
                d = lp.x - lt.x; ad = fabsf(d); llS += (ad < 1.f) ? 0.5f * d * d : ad - 0.5f;
                d = lp.y - lt.y; ad = fabsf(d); llS += (ad < 1.f) ? 0.5f * d * d : ad - 0.5f;
                d = lp.z - lt.z; ad = fabsf(d); llS += (ad < 1.f) ? 0.5f * d * d : ad - 0.5f;
                d = lp.w - lt.w; ad = fabsf(d); llS += (ad < 1.f) ? 0.5f * d * d : ad - 0.5f;
            }
        }
    }

    __shared__ float sr[3][4];
    __shared__ int si[4];
    float v0 = wred_f(ceS), v1 = wred_f(pceS), v2 = wred_f(llS);
    int v3 = wred_i(npS);
    const int w = threadIdx.x >> 6, ln = threadIdx.x & 63;
    if (ln == 0) { sr[0][w] = v0; sr[1][w] = v1; sr[2][w] = v2; si[w] = v3; }
    __syncthreads();
    if (threadIdx.x == 0) {
        float A = 0, B = 0, C = 0; int D = 0;
#pragma unroll
        for (int k = 0; k < 4; k++) { A += sr[0][k]; B += sr[1][k]; C += sr[2][k]; D += si[k]; }
        atomicAdd(&row_ce[r], A);
        atomicAdd(&row_pce[r], B);
        atomicAdd(loc_acc, C);
        atomicAdd(&row_np[r], D);
        atomicAdd(nm_acc, D);
    }
}

__device__ inline float ce_for_box0(const float* __restrict__ cp) {
    float c[NC];
#pragma unroll
    for (int j = 0; j < NC; j++) c[j] = cp[j];
    float m = c[0];
#pragma unroll
    for (int j = 1; j < NC; j++) m = fmaxf(m, c[j]);
    float s = 0.f;
#pragma unroll
    for (int j = 0; j < NC; j++) s += __expf(c[j] - m);
    return m + __logf(s) - c[0];
}

// Per-row mining + conf accumulation; LAST block finalizes output.
// Hot path (K >= #neg, always true on this data): conf_row = row_ce, no sort.
// Cold path: exact top-K via radix select (tie values identical -> sum exact).
__global__ void __launch_bounds__(256)
kB(const float* __restrict__ conf, const int* __restrict__ lab,
   const float* __restrict__ row_ce, const float* __restrict__ row_pce,
   const int* __restrict__ row_np, float* __restrict__ conf_acc,
   float* __restrict__ loc_acc, int* __restrict__ nm_acc,
   int* __restrict__ done, float* __restrict__ out) {
    const int r = blockIdx.x;
    const int np = row_np[r];
    const int K = min(3 * np, NB - 1);
    const int nneg = NB - np;

    float rowval = 0.f;
    if (K >= nneg) {
        rowval = row_ce[r];
    } else if (K <= 0) {
        rowval = row_pce[r];
    } else {
        __shared__ unsigned key[NB];
        __shared__ unsigned hist[256];
        __shared__ unsigned sb[2];
        for (int i = threadIdx.x; i < NB; i += 256) {
            const long box = (long)r * NB + i;
            unsigned k = 0u;
            if (lab[box] == 0) {
                float ce = ce_for_box0(conf + box * (long)NC);
                k = __float_as_uint(fmaxf(ce, 0.f));
            }
            key[i] = k;
        }
        __syncthreads();
        unsigned prefix = 0;
        int Kr = K;
        for (int round = 3; round >= 0; --round) {
            const int sh = round * 8;
            const unsigned pmask = (round == 3) ? 0u : (0xFFFFFFFFu << (8 * (round + 1)));
            for (int b = threadIdx.x; b < 256; b += 256) hist[b] = 0;
            __syncthreads();
            for (int i = threadIdx.x; i < NB; i += 256) {
                const unsigned k = key[i];
                if ((k & pmask) == prefix) atomicAdd(&hist[(k >> sh) & 255u], 1u);
            }
            __syncthreads();
            if (threadIdx.x == 0) {
                unsigned cum = 0; int b = 255;
                for (; b > 0; --b) {
                    const unsigned h = hist[b];
                    if (cum + h >= (unsigned)Kr) break;
                    cum += h;
                }
                sb[0] = cum; sb[1] = (unsigned)b;
            }
            __syncthreads();
            Kr -= (int)sb[0];
            prefix |= (sb[1] << sh);
            __syncthreads();
        }
        float local = 0.f;
        for (int i = threadIdx.x; i < NB; i += 256) {
            const unsigned k = key[i];
            if (k > prefix) local += __uint_as_float(k);
        }
        __shared__ float sred[4];
        float v = wred_f(local);
        const int w = threadIdx.x >> 6, ln = threadIdx.x & 63;
        if (ln == 0) sred[w] = v;
        __syncthreads();
        rowval = row_pce[r] + sred[0] + sred[1] + sred[2] + sred[3]
               + (float)Kr * __uint_as_float(prefix);
    }

    if (threadIdx.x == 0) {
        atomicAdd(conf_acc, rowval);
        __threadfence();
        const int old = atomicAdd(done, 1);
        if (old == BATCH - 1) {
            const float cf = atomicAdd(conf_acc, 0.f);
            const float lc = atomicAdd(loc_acc, 0.f);
            const int nm = atomicAdd(nm_acc, 0);
            out[0] = (lc + cf) / fmaxf((float)nm, 1.f);
        }
    }
}

extern "C" void kernel_launch(void* const* d_in, const int* in_sizes, int n_in,
                              void* d_out, int out_size, void* d_ws, size_t ws_size,
                              hipStream_t stream) {
    const float* locp = (const float*)d_in[0];
    const float* loct = (const float*)d_in[1];
    const float* conf = (const float*)d_in[2];
    const int* lab = (const int*)d_in[3];
    float* out = (float*)d_out;

    float* loc_acc = (float*)d_ws;
    float* conf_acc = loc_acc + 1;
    int* nm_acc = (int*)d_ws + 2;
    int* done = (int*)d_ws + 3;
    float* row_ce = (float*)d_ws + 16;
    float* row_pce = row_ce + BATCH;
    int* row_np = (int*)(row_pce + BATCH);

    hipMemsetAsync(d_ws, 0, 4096, stream);

    hipLaunchKernelGGL(kA, dim3(GXB, BATCH), dim3(256), 0, stream,
                       locp, loct, conf, lab, row_ce, row_pce, row_np, loc_acc, nm_acc);
    hipLaunchKernelGGL(kB, dim3(BATCH), dim3(256), 0, stream,
                       conf, lab, row_ce, row_pce, row_np, conf_acc, loc_acc, nm_acc, done, out);
}